// Round 9
// baseline (520.902 us; speedup 1.0000x reference)
//
#include <hip/hip_runtime.h>

// SimpleGRU scan: B=2048 seqs, T=2048 steps, H=32, O=2, fp32 backbone.
// Round-9: R8 structure (full-K 2-batch/wave, 1024 waves, shared trans)
// with the gate matmul moved from v_dot2_f32_f16 (~4cyc) to packed-f16
// v_pk_fma_f16 (2cyc, CDNA runs packed f16 at 2x fp32 vector rate):
//   per gate: 4 chains of 4 (pk_mul + 3 pk_fma), tree-combine with 3
//   pk_add_f16, horizontal+seed via ONE fdot2(acc,(1,1),seed).
//   42 cyc/gate vs 66 -> matmul issue 198 -> 126 for 2 batches.
// f16 accumulation at 4-deep chains: partial sums <=~0.25, rounding
// ~1e-4/chain; predicted absmax ~1.5-2.5e-3 (threshold 3.5e-3).
// Everything else identical to R8 (it measured: issue 352 matched model,
// exposed serial ~250 cyc at 1 wave/SIMD).

typedef _Float16 f16x2 __attribute__((ext_vector_type(2)));

__device__ __forceinline__ float fdot2(int a, int b, float c) {
    return __builtin_amdgcn_fdot2(__builtin_bit_cast(f16x2, a),
                                  __builtin_bit_cast(f16x2, b), c, false);
}

__device__ __forceinline__ int pack_pair(float a, float b) {
    f16x2 p;
    p.x = (_Float16)a;
    p.y = (_Float16)b;
    return __builtin_bit_cast(int, p);
}

__device__ __forceinline__ f16x2 asf16(int v) {
    return __builtin_bit_cast(f16x2, v);
}

__global__ __launch_bounds__(64, 1)
void gru_scan_kernel(const float* __restrict__ x,      // [B,T]
                     const float* __restrict__ w_ih,   // [96,1]
                     const float* __restrict__ w_hh,   // [96,32]
                     const float* __restrict__ b_ih,   // [96]
                     const float* __restrict__ b_hh,   // [96]
                     const float* __restrict__ head_w, // [2,32]
                     const float* __restrict__ head_b, // [2]
                     float* __restrict__ out,          // [B,2]
                     int T)
{
    const int l = (int)threadIdx.x;
    const int g = l >> 5;   // batch slot within wave
    const int j = l & 31;   // gate/hidden row
    const int b = (int)blockIdx.x * 2 + g;

    __shared__ __align__(16) _Float16 h16[2][32];   // [group][hidden] f16
    __shared__ float hf_s[2][32];                   // fp32 h for head
    __shared__ __align__(16) float x_s[2][2][32];   // [group][buf][step]

    // ---- per-lane weights: rows j (r), 32+j (z), 64+j (n), full K=32,
    // as 16 f16x2 pairs per gate = 48 int regs, asm-pinned ----
    int wR[16], wZ[16], wN[16];
    {
        const float* pR = w_hh + (     j) * 32;
        const float* pZ = w_hh + (32 + j) * 32;
        const float* pN = w_hh + (64 + j) * 32;
#pragma unroll
        for (int q = 0; q < 16; ++q) {
            wR[q] = pack_pair(pR[2*q], pR[2*q+1]);
            wZ[q] = pack_pair(pZ[2*q], pZ[2*q+1]);
            wN[q] = pack_pair(pN[2*q], pN[2*q+1]);
        }
    }
#pragma unroll
    for (int q = 0; q < 16; ++q) {
        asm volatile("" : "+v"(wR[q]), "+v"(wZ[q]), "+v"(wN[q]));
    }

    const int ONE2 = 0x3C003C00;   // f16x2 (1.0, 1.0) for horizontal fdot2

    // full-K: every lane computes complete dots -> plain per-row seeds
    const float wihr = w_ih[j];
    const float wihz = w_ih[32 + j];
    const float wihn = w_ih[64 + j];
    const float br   = b_ih[j]      + b_hh[j];
    const float bz   = b_ih[32 + j] + b_hh[32 + j];
    const float bni  = b_ih[64 + j];
    const float bnh  = b_hh[64 + j];

    const float* xrow   = x + (size_t)b * (size_t)T;
    const int    nchunk = T >> 5;   // 32-step chunks (T=2048 -> 64)

    float h = 0.0f;
    h16[g][j]    = (_Float16)0.0f;
    x_s[g][0][j] = xrow[j];
    float xnext  = (nchunk > 1) ? xrow[32 + j] : 0.0f;
    __builtin_amdgcn_wave_barrier();

    // own group's 32 h = 64 B = 4 broadcast b128 reads (group-disjoint banks)
    const int4* hq = (const int4*)(&h16[g][0]);

    for (int c = 0; c < nchunk; ++c) {
        const int buf = c & 1;
        const float* xs = &x_s[g][buf][0];
#pragma unroll 4
        for (int s = 0; s < 32; ++s) {
            const float xv = xs[s];                  // broadcast b32
            const int4 H0 = hq[0];   // h pairs 0..3
            const int4 H1 = hq[1];   // pairs 4..7
            const int4 H2 = hq[2];   // pairs 8..11
            const int4 H3 = hq[3];   // pairs 12..15
            const f16x2 h0x = asf16(H0.x), h0y = asf16(H0.y),
                        h0z = asf16(H0.z), h0w = asf16(H0.w);
            const f16x2 h1x = asf16(H1.x), h1y = asf16(H1.y),
                        h1z = asf16(H1.z), h1w = asf16(H1.w);
            const f16x2 h2x = asf16(H2.x), h2y = asf16(H2.y),
                        h2z = asf16(H2.z), h2w = asf16(H2.w);
            const f16x2 h3x = asf16(H3.x), h3y = asf16(H3.y),
                        h3z = asf16(H3.z), h3w = asf16(H3.w);

            // ---- gate r: 4 chains of 4 pk ops, tree combine ----
            f16x2 r0 = h0x * asf16(wR[ 0]);
            f16x2 r1 = h1x * asf16(wR[ 4]);
            f16x2 r2 = h2x * asf16(wR[ 8]);
            f16x2 r3 = h3x * asf16(wR[12]);
            r0 = __builtin_elementwise_fma(h0y, asf16(wR[ 1]), r0);
            r1 = __builtin_elementwise_fma(h1y, asf16(wR[ 5]), r1);
            r2 = __builtin_elementwise_fma(h2y, asf16(wR[ 9]), r2);
            r3 = __builtin_elementwise_fma(h3y, asf16(wR[13]), r3);
            r0 = __builtin_elementwise_fma(h0z, asf16(wR[ 2]), r0);
            r1 = __builtin_elementwise_fma(h1z, asf16(wR[ 6]), r1);
            r2 = __builtin_elementwise_fma(h2z, asf16(wR[10]), r2);
            r3 = __builtin_elementwise_fma(h3z, asf16(wR[14]), r3);
            r0 = __builtin_elementwise_fma(h0w, asf16(wR[ 3]), r0);
            r1 = __builtin_elementwise_fma(h1w, asf16(wR[ 7]), r1);
            r2 = __builtin_elementwise_fma(h2w, asf16(wR[11]), r2);
            r3 = __builtin_elementwise_fma(h3w, asf16(wR[15]), r3);
            const f16x2 rs = (r0 + r1) + (r2 + r3);

            // ---- gate z ----
            f16x2 z0 = h0x * asf16(wZ[ 0]);
            f16x2 z1 = h1x * asf16(wZ[ 4]);
            f16x2 z2 = h2x * asf16(wZ[ 8]);
            f16x2 z3 = h3x * asf16(wZ[12]);
            z0 = __builtin_elementwise_fma(h0y, asf16(wZ[ 1]), z0);
            z1 = __builtin_elementwise_fma(h1y, asf16(wZ[ 5]), z1);
            z2 = __builtin_elementwise_fma(h2y, asf16(wZ[ 9]), z2);
            z3 = __builtin_elementwise_fma(h3y, asf16(wZ[13]), z3);
            z0 = __builtin_elementwise_fma(h0z, asf16(wZ[ 2]), z0);
            z1 = __builtin_elementwise_fma(h1z, asf16(wZ[ 6]), z1);
            z2 = __builtin_elementwise_fma(h2z, asf16(wZ[10]), z2);
            z3 = __builtin_elementwise_fma(h3z, asf16(wZ[14]), z3);
            z0 = __builtin_elementwise_fma(h0w, asf16(wZ[ 3]), z0);
            z1 = __builtin_elementwise_fma(h1w, asf16(wZ[ 7]), z1);
            z2 = __builtin_elementwise_fma(h2w, asf16(wZ[11]), z2);
            z3 = __builtin_elementwise_fma(h3w, asf16(wZ[15]), z3);
            const f16x2 zs = (z0 + z1) + (z2 + z3);

            // ---- gate n (hidden side) ----
            f16x2 n0 = h0x * asf16(wN[ 0]);
            f16x2 n1 = h1x * asf16(wN[ 4]);
            f16x2 n2 = h2x * asf16(wN[ 8]);
            f16x2 n3 = h3x * asf16(wN[12]);
            n0 = __builtin_elementwise_fma(h0y, asf16(wN[ 1]), n0);
            n1 = __builtin_elementwise_fma(h1y, asf16(wN[ 5]), n1);
            n2 = __builtin_elementwise_fma(h2y, asf16(wN[ 9]), n2);
            n3 = __builtin_elementwise_fma(h3y, asf16(wN[13]), n3);
            n0 = __builtin_elementwise_fma(h0z, asf16(wN[ 2]), n0);
            n1 = __builtin_elementwise_fma(h1z, asf16(wN[ 6]), n1);
            n2 = __builtin_elementwise_fma(h2z, asf16(wN[10]), n2);
            n3 = __builtin_elementwise_fma(h3z, asf16(wN[14]), n3);
            n0 = __builtin_elementwise_fma(h0w, asf16(wN[ 3]), n0);
            n1 = __builtin_elementwise_fma(h1w, asf16(wN[ 7]), n1);
            n2 = __builtin_elementwise_fma(h2w, asf16(wN[11]), n2);
            n3 = __builtin_elementwise_fma(h3w, asf16(wN[15]), n3);
            const f16x2 ns = (n0 + n1) + (n2 + n3);

            // horizontal + seed in one fdot2 per gate
            const float rp = fdot2(__builtin_bit_cast(int, rs), ONE2,
                                   fmaf(xv, wihr, br));
            const float zp = fdot2(__builtin_bit_cast(int, zs), ONE2,
                                   fmaf(xv, wihz, bz));
            const float np = fdot2(__builtin_bit_cast(int, ns), ONE2, bnh);

            // shared-rcp sigmoid pair: r=1/(1+er), z=1/(1+ez)
            const float er = __builtin_amdgcn_exp2f(rp * -1.44269504088896f);
            const float ez = __builtin_amdgcn_exp2f(zp * -1.44269504088896f);
            const float A  = 1.0f + er;
            const float Bv = 1.0f + ez;
            const float inv = __builtin_amdgcn_rcpf(A * Bv);
            const float r  = Bv * inv;
            const float z  = A * inv;

            // n = tanh(xn + r*np)
            const float xn = fmaf(xv, wihn, bni);
            const float u  = fmaf(r, np, xn);
            const float et = __builtin_amdgcn_exp2f(u * 2.88539008177793f);
            const float ti = __builtin_amdgcn_rcpf(1.0f + et);
            const float n  = fmaf(-2.0f, ti, 1.0f);

            h = fmaf(z, h - n, n);                   // (1-z)*n + z*h
            __builtin_amdgcn_wave_barrier();
            h16[g][j] = (_Float16)h;                 // publish for next step
            __builtin_amdgcn_wave_barrier();         // in-order DS => RAW safe
        }
        if (c + 1 < nchunk) {
            x_s[g][1 - buf][j] = xnext;              // stage next chunk
            if (c + 2 < nchunk) xnext = xrow[(c + 2) * 32 + j];
            __builtin_amdgcn_wave_barrier();
        }
    }

    // ---- head: out[b,o] = head_b[o] + sum_k h[k]*head_w[o,k] (fp32 h) ----
    hf_s[g][j] = h;
    __builtin_amdgcn_wave_barrier();
    if (l < 4) {
        const int g2 = l >> 1, o = l & 1;
        float acc = head_b[o];
        const float* hw = head_w + o * 32;
#pragma unroll
        for (int k = 0; k < 32; ++k) acc = fmaf(hf_s[g2][k], hw[k], acc);
        out[((int)blockIdx.x * 2 + g2) * 2 + o] = acc;
    }
}

extern "C" void kernel_launch(void* const* d_in, const int* in_sizes, int n_in,
                              void* d_out, int out_size, void* d_ws, size_t ws_size,
                              hipStream_t stream) {
    const float* x      = (const float*)d_in[0];
    const float* w_ih   = (const float*)d_in[1];
    const float* w_hh   = (const float*)d_in[2];
    const float* b_ih   = (const float*)d_in[3];
    const float* b_hh   = (const float*)d_in[4];
    const float* head_w = (const float*)d_in[5];
    const float* head_b = (const float*)d_in[6];
    float* out = (float*)d_out;

    const int B = out_size / 2;          // O = 2
    const int T = in_sizes[0] / B;       // x is [B,T]

    dim3 grid(B / 2), block(64);
    hipLaunchKernelGGL(gru_scan_kernel, grid, block, 0, stream,
                       x, w_ih, w_hh, b_ih, b_hh, head_w, head_b, out, T);
}

// Round 10
// 487.010 us; speedup vs baseline: 1.0696x; 1.0696x over previous
//
#include <hip/hip_runtime.h>

// SimpleGRU scan: B=2048 seqs, T=2048 steps, H=32, O=2, fp32 backbone.
// Round-10: R8 (best, 465us) + two fixes from the R9 post-mortem.
// Model fitted R5-R9: ALL 2-MAC ops (dot2/pk_fma_f16/pk_fma_f32) ~4cyc =
// same MAC rate as scalar FMA; 96 MACs/step-pair => >=192cyc matmul issue
// per wave. R8's gap: 352 measured vs 274 accounted issue (~78cyc) + 52
// arch VGPRs < 48 weights + working set => AGPR-parking tax persists; and
// 8-deep dot chains put ~50-60cyc dep latency on the exposed path.
//  Fix 1: IN-LOOP empty asm pin of all 48 weights (zero instructions,
//         forces arch-VGPR residency every iteration).
//  Fix 2: dot chains 2x8 -> 4x4 (+6 adds issue, -25-30cyc critical path).
// Everything else identical to R8.

typedef _Float16 f16x2 __attribute__((ext_vector_type(2)));

__device__ __forceinline__ float fdot2(int a, int b, float c) {
    return __builtin_amdgcn_fdot2(__builtin_bit_cast(f16x2, a),
                                  __builtin_bit_cast(f16x2, b), c, false);
}

__device__ __forceinline__ int pack_pair(float a, float b) {
    f16x2 p;
    p.x = (_Float16)a;
    p.y = (_Float16)b;
    return __builtin_bit_cast(int, p);
}

__global__ __launch_bounds__(64, 1)
void gru_scan_kernel(const float* __restrict__ x,      // [B,T]
                     const float* __restrict__ w_ih,   // [96,1]
                     const float* __restrict__ w_hh,   // [96,32]
                     const float* __restrict__ b_ih,   // [96]
                     const float* __restrict__ b_hh,   // [96]
                     const float* __restrict__ head_w, // [2,32]
                     const float* __restrict__ head_b, // [2]
                     float* __restrict__ out,          // [B,2]
                     int T)
{
    const int l = (int)threadIdx.x;
    const int g = l >> 5;   // batch slot within wave
    const int j = l & 31;   // gate/hidden row
    const int b = (int)blockIdx.x * 2 + g;

    __shared__ __align__(16) _Float16 h16[2][32];   // [group][hidden] f16
    __shared__ float hf_s[2][32];                   // fp32 h for head
    __shared__ __align__(16) float x_s[2][2][32];   // [group][buf][step]

    // ---- per-lane weights: rows j (r), 32+j (z), 64+j (n), full K=32,
    // as 16 f16x2 pairs per gate = 48 int regs ----
    int wR[16], wZ[16], wN[16];
    {
        const float* pR = w_hh + (     j) * 32;
        const float* pZ = w_hh + (32 + j) * 32;
        const float* pN = w_hh + (64 + j) * 32;
#pragma unroll
        for (int q = 0; q < 16; ++q) {
            wR[q] = pack_pair(pR[2*q], pR[2*q+1]);
            wZ[q] = pack_pair(pZ[2*q], pZ[2*q+1]);
            wN[q] = pack_pair(pN[2*q], pN[2*q+1]);
        }
    }

    // full-K: every lane computes complete dots -> plain per-row seeds
    const float wihr = w_ih[j];
    const float wihz = w_ih[32 + j];
    const float wihn = w_ih[64 + j];
    const float br   = b_ih[j]      + b_hh[j];
    const float bz   = b_ih[32 + j] + b_hh[32 + j];
    const float bni  = b_ih[64 + j];
    const float bnh  = b_hh[64 + j];

    const float* xrow   = x + (size_t)b * (size_t)T;
    const int    nchunk = T >> 5;   // 32-step chunks (T=2048 -> 64)

    float h = 0.0f;
    h16[g][j]    = (_Float16)0.0f;
    x_s[g][0][j] = xrow[j];
    float xnext  = (nchunk > 1) ? xrow[32 + j] : 0.0f;
    __builtin_amdgcn_wave_barrier();

    // own group's 32 h = 64 B = 4 broadcast b128 reads (group-disjoint banks)
    const int4* hq = (const int4*)(&h16[g][0]);

    for (int c = 0; c < nchunk; ++c) {
        const int buf = c & 1;
        const float* xs = &x_s[g][buf][0];
#pragma unroll 4
        for (int s = 0; s < 32; ++s) {
            // Fix 1: in-loop pin — zero instructions, forces all 48 weight
            // values live in arch VGPRs at this point every iteration, so
            // AGPR-shuttling (the ~78cyc/step tax seen R3-R9) loses.
#pragma unroll
            for (int q = 0; q < 16; ++q) {
                asm volatile("" : "+v"(wR[q]), "+v"(wZ[q]), "+v"(wN[q]));
            }
            const float xv = xs[s];                  // broadcast b32
            const int4 H0 = hq[0];   // h pairs 0..3
            const int4 H1 = hq[1];   // pairs 4..7
            const int4 H2 = hq[2];   // pairs 8..11
            const int4 H3 = hq[3];   // pairs 12..15

            // Fix 2: 4 chains of 4 dot2 per gate (16 pairs = full K=32)
            float rA = fdot2(H0.x, wR[ 0], fmaf(xv, wihr, br));
            float zA = fdot2(H0.x, wZ[ 0], fmaf(xv, wihz, bz));
            float nA = fdot2(H0.x, wN[ 0], bnh);
            rA = fdot2(H0.y, wR[ 1], rA); zA = fdot2(H0.y, wZ[ 1], zA); nA = fdot2(H0.y, wN[ 1], nA);
            rA = fdot2(H0.z, wR[ 2], rA); zA = fdot2(H0.z, wZ[ 2], zA); nA = fdot2(H0.z, wN[ 2], nA);
            rA = fdot2(H0.w, wR[ 3], rA); zA = fdot2(H0.w, wZ[ 3], zA); nA = fdot2(H0.w, wN[ 3], nA);

            float rB = fdot2(H1.x, wR[ 4], 0.0f);
            float zB = fdot2(H1.x, wZ[ 4], 0.0f);
            float nB = fdot2(H1.x, wN[ 4], 0.0f);
            rB = fdot2(H1.y, wR[ 5], rB); zB = fdot2(H1.y, wZ[ 5], zB); nB = fdot2(H1.y, wN[ 5], nB);
            rB = fdot2(H1.z, wR[ 6], rB); zB = fdot2(H1.z, wZ[ 6], zB); nB = fdot2(H1.z, wN[ 6], nB);
            rB = fdot2(H1.w, wR[ 7], rB); zB = fdot2(H1.w, wZ[ 7], zB); nB = fdot2(H1.w, wN[ 7], nB);

            float rC = fdot2(H2.x, wR[ 8], 0.0f);
            float zC = fdot2(H2.x, wZ[ 8], 0.0f);
            float nC = fdot2(H2.x, wN[ 8], 0.0f);
            rC = fdot2(H2.y, wR[ 9], rC); zC = fdot2(H2.y, wZ[ 9], zC); nC = fdot2(H2.y, wN[ 9], nC);
            rC = fdot2(H2.z, wR[10], rC); zC = fdot2(H2.z, wZ[10], zC); nC = fdot2(H2.z, wN[10], nC);
            rC = fdot2(H2.w, wR[11], rC); zC = fdot2(H2.w, wZ[11], zC); nC = fdot2(H2.w, wN[11], nC);

            float rD = fdot2(H3.x, wR[12], 0.0f);
            float zD = fdot2(H3.x, wZ[12], 0.0f);
            float nD = fdot2(H3.x, wN[12], 0.0f);
            rD = fdot2(H3.y, wR[13], rD); zD = fdot2(H3.y, wZ[13], zD); nD = fdot2(H3.y, wN[13], nD);
            rD = fdot2(H3.z, wR[14], rD); zD = fdot2(H3.z, wZ[14], zD); nD = fdot2(H3.z, wN[14], nD);
            rD = fdot2(H3.w, wR[15], rD); zD = fdot2(H3.w, wZ[15], zD); nD = fdot2(H3.w, wN[15], nD);

            const float rp = (rA + rB) + (rC + rD);
            const float zp = (zA + zB) + (zC + zD);
            const float np = (nA + nB) + (nC + nD);

            // shared-rcp sigmoid pair: r=1/(1+er), z=1/(1+ez)
            const float er = __builtin_amdgcn_exp2f(rp * -1.44269504088896f);
            const float ez = __builtin_amdgcn_exp2f(zp * -1.44269504088896f);
            const float A  = 1.0f + er;
            const float Bv = 1.0f + ez;
            const float inv = __builtin_amdgcn_rcpf(A * Bv);
            const float r  = Bv * inv;
            const float z  = A * inv;

            // n = tanh(xn + r*np)
            const float xn = fmaf(xv, wihn, bni);
            const float u  = fmaf(r, np, xn);
            const float et = __builtin_amdgcn_exp2f(u * 2.88539008177793f);
            const float ti = __builtin_amdgcn_rcpf(1.0f + et);
            const float n  = fmaf(-2.0f, ti, 1.0f);

            h = fmaf(z, h - n, n);                   // (1-z)*n + z*h
            __builtin_amdgcn_wave_barrier();
            h16[g][j] = (_Float16)h;                 // publish for next step
            __builtin_amdgcn_wave_barrier();         // in-order DS => RAW safe
        }
        if (c + 1 < nchunk) {
            x_s[g][1 - buf][j] = xnext;              // stage next chunk
            if (c + 2 < nchunk) xnext = xrow[(c + 2) * 32 + j];
            __builtin_amdgcn_wave_barrier();
        }
    }

    // ---- head: out[b,o] = head_b[o] + sum_k h[k]*head_w[o,k] (fp32 h) ----
    hf_s[g][j] = h;
    __builtin_amdgcn_wave_barrier();
    if (l < 4) {
        const int g2 = l >> 1, o = l & 1;
        float acc = head_b[o];
        const float* hw = head_w + o * 32;
#pragma unroll
        for (int k = 0; k < 32; ++k) acc = fmaf(hf_s[g2][k], hw[k], acc);
        out[((int)blockIdx.x * 2 + g2) * 2 + o] = acc;
    }
}

extern "C" void kernel_launch(void* const* d_in, const int* in_sizes, int n_in,
                              void* d_out, int out_size, void* d_ws, size_t ws_size,
                              hipStream_t stream) {
    const float* x      = (const float*)d_in[0];
    const float* w_ih   = (const float*)d_in[1];
    const float* w_hh   = (const float*)d_in[2];
    const float* b_ih   = (const float*)d_in[3];
    const float* b_hh   = (const float*)d_in[4];
    const float* head_w = (const float*)d_in[5];
    const float* head_b = (const float*)d_in[6];
    float* out = (float*)d_out;

    const int B = out_size / 2;          // O = 2
    const int T = in_sizes[0] / B;       // x is [B,T]

    dim3 grid(B / 2), block(64);
    hipLaunchKernelGGL(gru_scan_kernel, grid, block, 0, stream,
                       x, w_ih, w_hh, b_ih, b_hh, head_w, head_b, out, T);
}